// Round 8
// baseline (36.522 us; speedup 1.0000x reference)
//
#include <hip/hip_runtime.h>
#include <float.h>

#define GDIM 12
#define NC   144          // GDIM*GDIM
#define FINF 1.0e9f
#define REPEAT 3          // DIAGNOSTIC: run relax phase 3x (identical work,
                          // identical output) to expose path_kernel in
                          // rocprof top-5 and split fixed vs relax cost.

// Padded 14x14 neighbor offsets in exact reference DIRS order.
__device__ __constant__ int POFF[8] = {-15, -14, -13, -1, 1, 13, 14, 15};

// Rotate within 16-lane DPP rows. Idle lanes 12..15 hold FINF => wrap-around
// IS the out-of-bounds guard; both directions are min'd, so convention is
// irrelevant.
template<int CTRL>
__device__ inline float rot(float x) {
    return __int_as_float(__builtin_amdgcn_update_dpp(
        __float_as_int(x), __float_as_int(x), CTRL, 0xf, 0xf, false));
}

// Sequential GS row update (7 VALU: min, min, 2xDPP, min3, add, min).
// Exact reference expression: D[i] = min(D[i], C[i] + min(8 neighbors)).
#define ROWU(i, C, D) {                                                    \
    float dm1 = ((i) > 0)        ? D[(i) > 0 ? (i)-1 : 0]        : FINF;   \
    float dp1 = ((i) < GDIM - 1) ? D[(i) < GDIM-1 ? (i)+1 : GDIM-1] : FINF;\
    float V   = fminf(dm1, dp1);                                           \
    float cm3 = fminf(V, D[(i)]);                                          \
    float nbr = fminf(fminf(rot<0x121>(cm3), rot<0x12F>(cm3)), V);         \
    D[(i)] = fminf(D[(i)], C[(i)] + nbr); }

#define SWEEP_DN(C, D) { _Pragma("unroll")                                 \
    for (int i = 0; i < GDIM; ++i) ROWU(i, C, D) }
#define SWEEP_UP(C, D) { _Pragma("unroll")                                 \
    for (int q = 0; q < GDIM; ++q) { const int i = GDIM - 1 - q; ROWU(i, C, D) } }

__global__ __launch_bounds__(64)
void path_kernel(const int* __restrict__ w,
                 const float* __restrict__ costs,
                 int* __restrict__ out) {
    const int l = threadIdx.x;      // lane 0..63
    const int g = l >> 4;           // problem group 0..3 within the wave
    const int j = l & 15;           // column (0..11 active, 12..15 idle=INF)
    const int pbase = blockIdx.x * 4;

    __shared__ int4  s_w4[NC];      // 4 problems' weights (576 ints)
    __shared__ float dl[4][200];    // 14x14 padded dist (196) + slack
    __shared__ int4  ml4[NC];       // 4 problems' masks (576 ints)
    int* s_w = (int*)s_w4;
    int* ml  = (int*)ml4;

    // uniform scalar loads of the 5-entry cost table (broadcast)
    const float cv0 = costs[0], cv1 = costs[1], cv2 = costs[2],
                cv3 = costs[3], cv4 = costs[4];

    // int4 coalesced staging of weights + mask zeroing + INF-fill dl
    const int4* wv = (const int4*)(w + (size_t)pbase * NC);
    const int4 zero4 = make_int4(0, 0, 0, 0);
    s_w4[l] = wv[l];            ml4[l] = zero4;
    s_w4[64 + l] = wv[64 + l];  ml4[64 + l] = zero4;
    if (l < 16) { s_w4[128 + l] = wv[128 + l]; ml4[128 + l] = zero4; }
    {
        float* dlf = &dl[0][0];
        #pragma unroll
        for (int t = 0; t < 13; ++t) { int idx = t * 64 + l; if (idx < 800) dlf[idx] = FINF; }
    }
    __syncthreads();

    const bool act = (j < GDIM);
    float* A = &dl[g][0];

    // c  = normal layout: lane j owns column j, reg i = row i  -> cell (i,j)
    // ct = transposed   : lane j owns row    j, reg i = col i  -> cell (j,i)
    float c[GDIM], ct[GDIM], d[GDIM];
    #pragma unroll
    for (int i = 0; i < GDIM; ++i) {
        int wiN = s_w[g * NC + i * GDIM + (act ? j : 0)];
        int idxT = act ? (g * NC + j * GDIM + i) : 0;
        int wiT = s_w[idxT];
        float cN = cv4, cT = cv4;
        cN = (wiN == 0) ? cv0 : cN;  cT = (wiT == 0) ? cv0 : cT;
        cN = (wiN == 1) ? cv1 : cN;  cT = (wiT == 1) ? cv1 : cT;
        cN = (wiN == 2) ? cv2 : cN;  cT = (wiT == 2) ? cv2 : cT;
        cN = (wiN == 3) ? cv3 : cN;  cT = (wiT == 3) ? cv3 : cT;
        c[i]  = act ? cN : FINF;
        ct[i] = act ? cT : FINF;
        d[i] = FINF;
    }

    // DIAGNOSTIC repeat: identical relax phase REPEAT times. Each rep
    // reinits d and runs to convergence; dl interior is rewritten every
    // cycle, border stays INF; output is identical across reps.
    #pragma unroll 1
    for (int rep = 0; rep < REPEAT; ++rep) {
        #pragma unroll
        for (int i = 0; i < GDIM; ++i) d[i] = FINF;
        if (j == 0) d[0] = c[0];    // source cell (0,0)
        asm volatile("" : "+v"(d[0]));   // keep reps opaque (no folding)

        // Cycle: {down, up} normal (vertical-monotone segments instant),
        // transpose, {right, left} transposed (horizontal-monotone instant),
        // transpose back; convergence by snapshot compare (monotone
        // decrease => d<dp anywhere <=> changed; clean cycle <=> fixed
        // point). Cap 40 cycles = 160 GS sweeps >= reference's 144-sweep
        // Jacobi guarantee (GS dominates Jacobi pointwise).
        for (int cyc = 0; cyc < 40; ++cyc) {
            float dp[GDIM];
            #pragma unroll
            for (int i = 0; i < GDIM; ++i) dp[i] = d[i];

            SWEEP_DN(c, d)
            SWEEP_UP(c, d)

            if (act) {
                #pragma unroll
                for (int i = 0; i < GDIM; ++i) A[(i + 1) * 14 + (j + 1)] = d[i];
                #pragma unroll
                for (int i = 0; i < GDIM; ++i) d[i] = A[(j + 1) * 14 + (i + 1)];
            }

            SWEEP_DN(ct, d)
            SWEEP_UP(ct, d)

            if (act) {
                #pragma unroll
                for (int i = 0; i < GDIM; ++i) A[(j + 1) * 14 + (i + 1)] = d[i];
                #pragma unroll
                for (int i = 0; i < GDIM; ++i) d[i] = A[(i + 1) * 14 + (j + 1)];
            }

            bool ch = false;
            #pragma unroll
            for (int i = 0; i < GDIM; ++i) ch = ch | (d[i] < dp[i]);
            if (__ballot(ch) == 0ull) break;
        }
    }
    __syncthreads();

    // backtrack: 4 walkers (lanes 0/16/32/48) in parallel on dl (already
    // populated in normal layout by the final T2). INF border keeps reads
    // in-bounds; first-wins strict-< scan in DIRS order == reference
    // argmin over (valid ? dist : INF).
    if (j == 0) {
        int a = 12 * 14 + 12;                 // padded addr of (11,11)
        ml[g * NC + NC - 1] = 1;
        int guard = 0;
        while (a != (1 * 14 + 1) && guard < 200) {
            ++guard;
            float best = FLT_MAX; int ba = a;
            #pragma unroll
            for (int dd = 0; dd < 8; ++dd) {
                int na = a + POFF[dd];
                float v = dl[g][na];
                if (v < best) { best = v; ba = na; }   // first-wins tie
            }
            a = ba;
            int ii = a / 14 - 1, jj = a % 14 - 1;
            ml[g * NC + ii * GDIM + jj] = 1;
        }
    }
    __syncthreads();

    // int4 coalesced store (writes every output element; no stale state)
    int4* ov = (int4*)(out + (size_t)pbase * NC);
    ov[l] = ml4[l];
    ov[64 + l] = ml4[64 + l];
    if (l < 16) ov[128 + l] = ml4[128 + l];
}

extern "C" void kernel_launch(void* const* d_in, const int* in_sizes, int n_in,
                              void* d_out, int out_size, void* d_ws, size_t ws_size,
                              hipStream_t stream) {
    const int*   w     = (const int*)d_in[0];
    const float* costs = (const float*)d_in[1];
    int*         out   = (int*)d_out;
    const int K = in_sizes[0] / NC;          // 8192 problems
    path_kernel<<<dim3(K / 4), dim3(64), 0, stream>>>(w, costs, out);
}

// Round 9
// 20.921 us; speedup vs baseline: 1.7457x; 1.7457x over previous
//
#include <hip/hip_runtime.h>
#include <float.h>

#define GDIM 12
#define NC   144          // GDIM*GDIM
#define FINF 1.0e9f

// DPP lane permutes within 16-lane rows.
// 0x121/0x12F: row_ror 1/15 (idle lanes 12..15 = FINF are the boundary guard;
// both directions min'd, so convention is irrelevant).
// 0xB1/0x4E: quad_perm xor1/xor2; 0x141: row_half_mirror; 0x140: row_mirror.
template<int CTRL>
__device__ inline float rot(float x) {
    return __int_as_float(__builtin_amdgcn_update_dpp(
        __float_as_int(x), __float_as_int(x), CTRL, 0xf, 0xf, false));
}

// Sequential GS row update (7 VALU). Exact reference expression:
// D[i] = min(D[i], C[i] + min(8 neighbors)).
#define ROWU(i, C, D) {                                                    \
    float dm1 = ((i) > 0)        ? D[(i) > 0 ? (i)-1 : 0]        : FINF;   \
    float dp1 = ((i) < GDIM - 1) ? D[(i) < GDIM-1 ? (i)+1 : GDIM-1] : FINF;\
    float V   = fminf(dm1, dp1);                                           \
    float cm3 = fminf(V, D[(i)]);                                          \
    float nbr = fminf(fminf(rot<0x121>(cm3), rot<0x12F>(cm3)), V);         \
    D[(i)] = fminf(D[(i)], C[(i)] + nbr); }

#define SWEEP_DN(C, D) { _Pragma("unroll")                                 \
    for (int i = 0; i < GDIM; ++i) ROWU(i, C, D) }
#define SWEEP_UP(C, D) { _Pragma("unroll")                                 \
    for (int q = 0; q < GDIM; ++q) { const int i = GDIM - 1 - q; ROWU(i, C, D) } }

__global__ __launch_bounds__(256)
void path_kernel(const int* __restrict__ w,
                 const float* __restrict__ costs,
                 int* __restrict__ out) {
    const int t  = threadIdx.x;     // 0..255
    const int wv = t >> 6;          // wave 0..3 (fully independent)
    const int l  = t & 63;          // lane 0..63
    const int g  = l >> 4;          // problem group 0..3 within the wave
    const int j  = l & 15;          // column (0..11 active, 12..15 idle=INF)
    const int pw = blockIdx.x * 16 + wv * 4;   // this wave's first problem

    __shared__ int4  s_w4[4][NC];   // per-wave weights (4 problems each)
    __shared__ float dl[4][4][200]; // per-wave per-group 14x14 padded dist
    __shared__ int   ml[4][4 * NC]; // per-wave masks

    // prefetch this wave's weights first (hide HBM latency under LDS init)
    const int4* wvp = (const int4*)(w + (size_t)pw * NC);
    int4 wA = wvp[l];
    int4 wB = wvp[64 + l];
    int4 wC = (l < 16) ? wvp[128 + l] : make_int4(0, 0, 0, 0);

    // uniform scalar loads of the 5-entry cost table (broadcast)
    const float cv0 = costs[0], cv1 = costs[1], cv2 = costs[2],
                cv3 = costs[3], cv4 = costs[4];

    // per-wave LDS init (no cross-wave sharing -> no barriers anywhere)
    int* mlw = ml[wv];
    #pragma unroll
    for (int q = 0; q < 9; ++q) mlw[q * 64 + l] = 0;
    float* dlw = &dl[wv][0][0];
    #pragma unroll
    for (int q = 0; q < 13; ++q) { int idx = q * 64 + l; if (idx < 800) dlw[idx] = FINF; }

    s_w4[wv][l] = wA;
    s_w4[wv][64 + l] = wB;
    if (l < 16) s_w4[wv][128 + l] = wC;

    const bool act = (j < GDIM);
    const int* sw = (const int*)s_w4[wv];
    float* A = &dl[wv][g][0];

    // c  = normal layout: lane j owns column j, reg i = row i  -> cell (i,j)
    // ct = transposed   : lane j owns row    j, reg i = col i  -> cell (j,i)
    float c[GDIM], ct[GDIM], d[GDIM];
    #pragma unroll
    for (int i = 0; i < GDIM; ++i) {
        int wiN = sw[g * NC + i * GDIM + (act ? j : 0)];
        int wiT = sw[act ? (g * NC + j * GDIM + i) : 0];
        float cN = cv4, cT = cv4;
        cN = (wiN == 0) ? cv0 : cN;  cT = (wiT == 0) ? cv0 : cT;
        cN = (wiN == 1) ? cv1 : cN;  cT = (wiT == 1) ? cv1 : cT;
        cN = (wiN == 2) ? cv2 : cN;  cT = (wiT == 2) ? cv2 : cT;
        cN = (wiN == 3) ? cv3 : cN;  cT = (wiT == 3) ? cv3 : cT;
        c[i]  = act ? cN : FINF;
        ct[i] = act ? cT : FINF;
        d[i]  = FINF;
    }
    if (j == 0) d[0] = c[0];        // source cell (0,0)

    // Cycle: {down,up} normal (vertical-monotone segments instant), LDS
    // transpose, {right,left} transposed (horizontal-monotone instant),
    // transpose back; convergence by snapshot compare. Cap 40 cycles = 160
    // GS sweeps >= reference's 144-sweep Jacobi guarantee (GS dominates
    // Jacobi pointwise). Monotone relaxation -> reference's exact f32
    // fixed point (identical per-update expressions, min exact).
    for (int cyc = 0; cyc < 40; ++cyc) {
        float dp[GDIM];
        #pragma unroll
        for (int i = 0; i < GDIM; ++i) dp[i] = d[i];

        SWEEP_DN(c, d)
        SWEEP_UP(c, d)

        if (act) {
            #pragma unroll
            for (int i = 0; i < GDIM; ++i) A[(i + 1) * 14 + (j + 1)] = d[i];
            #pragma unroll
            for (int i = 0; i < GDIM; ++i) d[i] = A[(j + 1) * 14 + (i + 1)];
        }

        SWEEP_DN(ct, d)
        SWEEP_UP(ct, d)

        if (act) {
            #pragma unroll
            for (int i = 0; i < GDIM; ++i) A[(j + 1) * 14 + (i + 1)] = d[i];
            #pragma unroll
            for (int i = 0; i < GDIM; ++i) d[i] = A[(i + 1) * 14 + (j + 1)];
        }

        bool ch = false;
        #pragma unroll
        for (int i = 0; i < GDIM; ++i) ch = ch | (d[i] < dp[i]);
        if (__ballot(ch) == 0ull) break;
    }

    // ---- parallel backtrack: 16 lanes per group cooperate ----
    // Lanes j<8 each load one neighbor (padded DIRS offsets -15,-14,-13,
    // -1,1,13,14,15 == j-15 | -1 | 1 | j+8); 4-step DPP min-butterfly
    // (min is idempotent -> quad xor1, xor2, half-mirror, mirror covers 16);
    // ballot lowest-set-bit = lowest dir index among ties = reference's
    // first-wins argmin. a = padded idx, n = flat idx (n-step = a-step+2*di).
    {
        int* mlg = mlw + g * NC;
        const int offj = (j < 3) ? (j - 15) : (j == 3) ? -1 : (j == 4) ? 1 : (j + 8);
        int a = 12 * 14 + 12;       // padded (11,11)
        int n = NC - 1;             // flat 143
        if (j == 0) mlg[n] = 1;
        const int target = 1 * 14 + 1;
        for (int s = 0; s < NC; ++s) {
            if (__ballot(a != target) == 0ull) break;
            float v = (j < 8) ? A[a + offj] : FINF;   // in-bounds even when done
            float m = v;
            m = fminf(m, rot<0xB1>(m));    // xor1 within quads
            m = fminf(m, rot<0x4E>(m));    // xor2 -> min of each quad
            m = fminf(m, rot<0x141>(m));   // half-mirror -> min of 8
            m = fminf(m, rot<0x140>(m));   // mirror -> min of 16
            unsigned long long bal = __ballot((j < 8) & (v == m));
            int mask8 = (int)(bal >> (g * 16)) & 0xFF;
            int bidx = __ffs(mask8) - 1;   // first-wins tie (lowest dir idx)
            if (a != target) {
                int off = (bidx < 3) ? (bidx - 15) : (bidx == 3) ? -1
                        : (bidx == 4) ? 1 : (bidx + 8);
                int adj = (bidx < 3) ? 2 : (bidx > 4) ? -2 : 0;
                a += off;
                n += off + adj;
                if (j == 0) mlg[n] = 1;
            }
        }
    }

    // ---- int4 coalesced store (writes every output element) ----
    int4* ov = (int4*)(out + (size_t)pw * NC);
    const int4* ml4w = (const int4*)mlw;
    ov[l] = ml4w[l];
    ov[64 + l] = ml4w[64 + l];
    if (l < 16) ov[128 + l] = ml4w[128 + l];
}

extern "C" void kernel_launch(void* const* d_in, const int* in_sizes, int n_in,
                              void* d_out, int out_size, void* d_ws, size_t ws_size,
                              hipStream_t stream) {
    const int*   w     = (const int*)d_in[0];
    const float* costs = (const float*)d_in[1];
    int*         out   = (int*)d_out;
    const int K = in_sizes[0] / NC;          // 8192 problems
    path_kernel<<<dim3(K / 16), dim3(256), 0, stream>>>(w, costs, out);
}